// Round 1
// baseline (2168.624 us; speedup 1.0000x reference)
//
#include <hip/hip_runtime.h>
#include <stdint.h>

#define N_NODES 100000
#define E_EDGES 1600000
#define INDIM 128
#define DD 64
#define HH 16
#define SS 8
#define HS 128            // H*S
#define GG 512
#define PENN 128
#define CC 10
#define F_OUT 384
#define BN_EPS 1e-5f

// ---------------- degree ----------------
__global__ void k_init_deg(float* deg){
    int n = blockIdx.x*256 + threadIdx.x;
    if(n < N_NODES) deg[n] = 1.0f;   // self loop
}

__global__ void k_deg(const int* __restrict__ row, float* deg){
    int e = blockIdx.x*256 + threadIdx.x;
    if(e < E_EDGES) atomicAdd(&deg[row[e]], 1.0f);
}

// ---------------- xh = sigmoid(x @ fc_w^T + b); y0 = xh/deg; agg1 = y0 (self loop) ----------------
__global__ __launch_bounds__(256) void k_xh(const float* __restrict__ x, const float* __restrict__ fc_w,
                     const float* __restrict__ fc_b, const float* __restrict__ deg,
                     float* __restrict__ xh, float* __restrict__ ybuf, float* __restrict__ agg1){
    __shared__ float wlds[INDIM][DD];   // fc_w[d][k] -> wlds[k][d]
    int tid = threadIdx.x;
    for(int i = tid; i < INDIM*DD; i += 256){
        int d = i / INDIM, k = i % INDIM;
        wlds[k][d] = fc_w[i];
    }
    __syncthreads();
    int gid = blockIdx.x*256 + tid;
    if(gid >= N_NODES*DD) return;
    int n = gid >> 6, d = gid & 63;
    const float* xr = x + (size_t)n*INDIM;
    float acc = fc_b[d];
    #pragma unroll 8
    for(int k = 0; k < INDIM; ++k) acc = fmaf(xr[k], wlds[k][d], acc);
    float s = 1.0f/(1.0f + expf(-acc));
    xh[gid] = s;
    float y = s / deg[n];
    ybuf[gid] = y;
    agg1[gid] = y;
}

// ---------------- scatter: agg[col] += y[row], thread per (edge, d) ----------------
__global__ void k_scatter(const int* __restrict__ row, const int* __restrict__ col,
                          const float* __restrict__ y, float* __restrict__ agg){
    int t = blockIdx.x*256 + threadIdx.x;       // e*64 + d  (E*64 = 102.4M < 2^31)
    if(t >= E_EDGES*64) return;
    int e = t >> 6;
    int d = t & 63;
    int r = row[e], c = col[e];
    atomicAdd(&agg[(size_t)c*DD + d], y[(size_t)r*DD + d]);
}

// ---------------- cur = agg @ w^T + b ; optionally y_next = cur/deg, agg_next = y_next ----------------
__global__ __launch_bounds__(256) void k_lin(const float* __restrict__ agg, const float* __restrict__ w,
                     const float* __restrict__ b, const float* __restrict__ deg,
                     float* __restrict__ cur, float* __restrict__ ynext, float* __restrict__ aggnext,
                     int make_next){
    __shared__ float wlds[DD][DD];   // w[d][k] -> wlds[k][d]
    int tid = threadIdx.x;
    for(int i = tid; i < DD*DD; i += 256){
        int d = i / DD, k = i % DD;
        wlds[k][d] = w[i];
    }
    __syncthreads();
    int gid = blockIdx.x*256 + tid;
    if(gid >= N_NODES*DD) return;
    int n = gid >> 6, d = gid & 63;
    const float* ar = agg + (size_t)n*DD;
    float acc = b[d];
    #pragma unroll 8
    for(int k = 0; k < DD; ++k) acc = fmaf(ar[k], wlds[k][d], acc);
    cur[gid] = acc;
    if(make_next){
        float yv = acc / deg[n];
        ynext[gid] = yv;
        aggnext[gid] = yv;
    }
}

// ---------------- z1 = A@z0, z2 = A@z1 (A from relu'd upper-tri params, symmetrized) ----------------
__global__ void k_z(const float* __restrict__ adj_hidden, const float* __restrict__ z0,
                    float* __restrict__ z1, float* __restrict__ z2){
    __shared__ float A[HH][SS][SS];
    __shared__ float zb[HH][SS][DD];
    int tid = threadIdx.x;
    for(int i = tid; i < HH*SS*SS; i += 256) ((float*)A)[i] = 0.0f;
    __syncthreads();
    for(int i = tid; i < HH*28; i += 256){
        int h = i / 28, p = i % 28;
        int iu = 0, ju = 0, cnt = 0;
        for(int a = 0; a < SS-1; ++a){
            int rl = SS-1-a;
            if(p < cnt + rl){ iu = a; ju = a + 1 + (p - cnt); break; }
            cnt += rl;
        }
        float v = adj_hidden[i];
        v = v > 0.f ? v : 0.f;
        A[h][iu][ju] = v;
        A[h][ju][iu] = v;
    }
    __syncthreads();
    for(int i = tid; i < HH*SS*DD; i += 256){
        int h = i >> 9, a = (i >> 6) & 7, d = i & 63;
        float acc = 0.f;
        #pragma unroll
        for(int bb = 0; bb < SS; ++bb) acc += A[h][a][bb] * z0[(h*SS+bb)*DD + d];
        z1[i] = acc;
        zb[h][a][d] = acc;
    }
    __syncthreads();
    for(int i = tid; i < HH*SS*DD; i += 256){
        int h = i >> 9, a = (i >> 6) & 7, d = i & 63;
        float acc = 0.f;
        #pragma unroll
        for(int bb = 0; bb < SS; ++bb) acc += A[h][a][bb] * zb[h][bb][d];
        z2[i] = acc;
    }
}

// ---------------- graph boundaries from sorted batch ----------------
__global__ void k_bounds(const int* __restrict__ batch, int* __restrict__ start){
    int n = blockIdx.x*256 + threadIdx.x;
    if(n >= N_NODES) return;
    int b = batch[n];
    int prev = (n == 0) ? -1 : batch[n-1];
    for(int g = prev + 1; g <= b; ++g) start[g] = n;
    if(n == N_NODES-1){
        for(int g = b + 1; g <= GG; ++g) start[g] = N_NODES;
    }
}

// ---------------- per-graph feature reduce: P[g][hs] = sum_n zx * (z[hs]·cur[n]) ----------------
__global__ __launch_bounds__(256) void k_feat(const float* __restrict__ z, const float* __restrict__ cur,
                      const int* __restrict__ start, float* __restrict__ P,
                      float* __restrict__ zxbuf, int step0){
    __shared__ float zt[DD][HS];     // z[hs][k] -> zt[k][hs]
    __shared__ float curl[2][DD];
    __shared__ float red[HS];
    int tid = threadIdx.x;
    for(int i = tid; i < HS*DD; i += 256){
        int hs = i >> 6, k = i & 63;
        zt[k][hs] = z[i];
    }
    int g = blockIdx.x;
    int s0 = start[g], s1 = start[g+1];
    __syncthreads();
    int grp = tid >> 7;
    int hs = tid & 127;
    float acc = 0.0f;
    for(int base = s0; base < s1; base += 2){
        if(tid < 128){
            int nn = base + (tid >> 6);
            if(nn < s1) curl[tid >> 6][tid & 63] = cur[(size_t)nn*DD + (tid & 63)];
        }
        __syncthreads();
        int n = base + grp;
        if(n < s1){
            float dot = 0.f;
            #pragma unroll 8
            for(int k = 0; k < DD; ++k) dot = fmaf(zt[k][hs], curl[grp][k], dot);
            if(step0){
                zxbuf[(size_t)n*HS + hs] = dot;
                acc = fmaf(dot, dot, acc);
            } else {
                float zx = zxbuf[(size_t)n*HS + hs];
                acc = fmaf(zx, dot, acc);
            }
        }
        __syncthreads();
    }
    if(grp == 1) red[hs] = acc;
    __syncthreads();
    if(grp == 0) P[(size_t)g*HS + hs] = acc + red[hs];
}

// ---------------- scrambled reshape: out_pre[r][i*128+c] = P_i[g,h,s] ----------------
__global__ void k_outpre(const float* __restrict__ P, float* __restrict__ outp){
    int idx = blockIdx.x*256 + threadIdx.x;
    if(idx >= GG*F_OUT) return;
    int r = idx / F_OUT, j = idx % F_OUT;
    int i = j >> 7, c = j & 127;
    int g = ((r & 63) << 3) + (c >> 4);
    int h = c & 15, s = r >> 6;
    int hs = h*SS + s;
    outp[idx] = P[((size_t)i*GG + g)*HS + hs];
}

// ---------------- batchnorm stats per column (training-mode batch stats) ----------------
__global__ void k_bnstats(const float* __restrict__ outp, const float* __restrict__ gamma,
                          const float* __restrict__ beta, float* __restrict__ scale_,
                          float* __restrict__ shift_){
    int j = blockIdx.x;     // 384 columns
    int t = threadIdx.x;    // 64 threads
    float v[8];
    float sum = 0.f;
    #pragma unroll
    for(int i = 0; i < 8; ++i){ v[i] = outp[(size_t)(t*8+i)*F_OUT + j]; sum += v[i]; }
    #pragma unroll
    for(int off = 32; off; off >>= 1) sum += __shfl_down(sum, off);
    sum = __shfl(sum, 0);
    float mean = sum / (float)GG;
    float sq = 0.f;
    #pragma unroll
    for(int i = 0; i < 8; ++i){ float d = v[i] - mean; sq = fmaf(d, d, sq); }
    #pragma unroll
    for(int off = 32; off; off >>= 1) sq += __shfl_down(sq, off);
    if(t == 0){
        float var = sq / (float)GG;
        float rstd = rsqrtf(var + BN_EPS);
        float sc = rstd * gamma[j];
        scale_[j] = sc;
        shift_[j] = beta[j] - mean*sc;
    }
}

// ---------------- BN apply + fc1 + relu + fc2 + log_softmax ----------------
__global__ __launch_bounds__(128) void k_mlp(const float* __restrict__ outp, const float* __restrict__ scale_,
                     const float* __restrict__ shift_, const float* __restrict__ fc1w,
                     const float* __restrict__ fc1b, const float* __restrict__ fc2w,
                     const float* __restrict__ fc2b, float* __restrict__ out){
    __shared__ float nrm[F_OUT];
    __shared__ float hid[PENN];
    __shared__ float logit[CC];
    int r = blockIdx.x, t = threadIdx.x;
    for(int j = t; j < F_OUT; j += 128)
        nrm[j] = fmaf(outp[(size_t)r*F_OUT + j], scale_[j], shift_[j]);
    __syncthreads();
    float acc = fc1b[t];
    #pragma unroll 8
    for(int j = 0; j < F_OUT; ++j) acc = fmaf(nrm[j], fc1w[(size_t)t*F_OUT + j], acc);
    hid[t] = acc > 0.f ? acc : 0.f;
    __syncthreads();
    if(t < CC){
        float a = fc2b[t];
        #pragma unroll
        for(int p = 0; p < PENN; ++p) a = fmaf(hid[p], fc2w[t*PENN + p], a);
        logit[t] = a;
    }
    __syncthreads();
    if(t < CC){
        float m = logit[0];
        #pragma unroll
        for(int c = 1; c < CC; ++c) m = fmaxf(m, logit[c]);
        float se = 0.f;
        #pragma unroll
        for(int c = 0; c < CC; ++c) se += expf(logit[c] - m);
        out[r*CC + t] = logit[t] - m - logf(se);
    }
}

extern "C" void kernel_launch(void* const* d_in, const int* in_sizes, int n_in,
                              void* d_out, int out_size, void* d_ws, size_t ws_size,
                              hipStream_t stream){
    const float* x      = (const float*)d_in[0];
    const int*   edges  = (const int*)d_in[1];
    const int*   batch  = (const int*)d_in[2];
    const float* adjh   = (const float*)d_in[3];
    const float* fh     = (const float*)d_in[4];   // z0
    const float* fc_w   = (const float*)d_in[5];
    const float* fc_b   = (const float*)d_in[6];
    const float* rw_w   = (const float*)d_in[7];
    const float* rw_b   = (const float*)d_in[8];
    const float* gamma  = (const float*)d_in[9];
    const float* beta   = (const float*)d_in[10];
    const float* fc1w   = (const float*)d_in[11];
    const float* fc1b   = (const float*)d_in[12];
    const float* fc2w   = (const float*)d_in[13];
    const float* fc2b   = (const float*)d_in[14];
    float* out = (float*)d_out;

    const int* row = edges;
    const int* col = edges + E_EDGES;

    // workspace carve-up
    size_t off = 0;
    auto alloc_f = [&](size_t nf) -> float* {
        float* p = (float*)((char*)d_ws + off);
        off += nf * sizeof(float);
        off = (off + 255) & ~(size_t)255;
        return p;
    };
    float* deg   = alloc_f(N_NODES);
    float* xh    = alloc_f((size_t)N_NODES*DD);
    float* ybuf  = alloc_f((size_t)N_NODES*DD);
    float* agg1  = alloc_f((size_t)N_NODES*DD);
    float* agg2  = alloc_f((size_t)N_NODES*DD);
    float* cur1  = alloc_f((size_t)N_NODES*DD);
    float* cur2  = alloc_f((size_t)N_NODES*DD);
    float* zx    = alloc_f((size_t)N_NODES*HS);
    float* z1    = alloc_f(HH*SS*DD);
    float* z2    = alloc_f(HH*SS*DD);
    float* P     = alloc_f((size_t)3*GG*HS);
    float* outp  = alloc_f((size_t)GG*F_OUT);
    float* scl   = alloc_f(F_OUT);
    float* shf   = alloc_f(F_OUT);
    int*   start = (int*)alloc_f(GG + 1);

    int blkN   = (N_NODES + 255)/256;
    int blkE   = (E_EDGES + 255)/256;
    int blkND  = (N_NODES*DD + 255)/256;
    int blkEsc = (E_EDGES*64 + 255)/256;

    k_init_deg<<<blkN, 256, 0, stream>>>(deg);
    k_deg<<<blkE, 256, 0, stream>>>(row, deg);
    k_xh<<<blkND, 256, 0, stream>>>(x, fc_w, fc_b, deg, xh, ybuf, agg1);
    k_scatter<<<blkEsc, 256, 0, stream>>>(row, col, ybuf, agg1);
    k_lin<<<blkND, 256, 0, stream>>>(agg1, rw_w, rw_b, deg, cur1, ybuf, agg2, 1);
    k_scatter<<<blkEsc, 256, 0, stream>>>(row, col, ybuf, agg2);
    k_lin<<<blkND, 256, 0, stream>>>(agg2, rw_w + DD*DD, rw_b + DD, deg, cur2, nullptr, nullptr, 0);
    k_z<<<1, 256, 0, stream>>>(adjh, fh, z1, z2);
    k_bounds<<<blkN, 256, 0, stream>>>(batch, start);
    k_feat<<<GG, 256, 0, stream>>>(fh, xh,   start, P,            zx, 1);
    k_feat<<<GG, 256, 0, stream>>>(z1, cur1, start, P + GG*HS,    zx, 0);
    k_feat<<<GG, 256, 0, stream>>>(z2, cur2, start, P + 2*GG*HS,  zx, 0);
    k_outpre<<<(GG*F_OUT + 255)/256, 256, 0, stream>>>(P, outp);
    k_bnstats<<<F_OUT, 64, 0, stream>>>(outp, gamma, beta, scl, shf);
    k_mlp<<<GG, 128, 0, stream>>>(outp, scl, shf, fc1w, fc1b, fc2w, fc2b, out);
}